// Round 1
// baseline (233.735 us; speedup 1.0000x reference)
//
#include <hip/hip_runtime.h>
#include <math.h>

// PCEN: out = (x / (smooth + eps)^alpha + delta)^r - delta^r
// smooth[0]=x[0]; smooth[t] = (1-S)*smooth[t-1] + S*x[t]
// x: [64,128,4096] fp32 -> 8192 rows of T=4096.
//
// One block of 256 threads per row, PER=16 elements per thread:
//  - 4 independent float4 loads/thread (64B-chunked per lane; L1 absorbs the
//    intra-wave line re-touch, HBM traffic is exact) -> 4x the MLP of the
//    previous 1024-thread/PER=4 version.
//  - 8 blocks/CU (vs 2) so sync-split phases of different rows overlap.
//  - Affine-map scan: per-thread composition KEEPS the per-element offsets
//    B_i, so the replay is smooth_i = A^(i+1)*y_in + B_i with compile-time
//    constant powers: 16 INDEPENDENT fmas, no dependent recurrence chain.
//  - 6-step wave shfl scan + 4-entry LDS cross-wave combine (was 16).
// Transcendentals stay raw v_log/v_exp/v_sqrt (y+eps in [1e-6, ~1], safe).

#define T_LEN 4096
#define BLOCK 256
#define PER   16   // 256*16 = 4096
#define NWAVE (BLOCK / 64)

__global__ __launch_bounds__(BLOCK) void pcen_kernel(const float* __restrict__ x,
                                                     float* __restrict__ out) {
    constexpr float A_COEF = 0.975f;   // 1 - S
    constexpr float S_COEF = 0.025f;   // S
    constexpr float ALPHA  = 0.98f;
    constexpr float EPS    = 1e-6f;
    constexpr float DELTA  = 2.0f;
    constexpr float SQRT_DELTA = 1.4142135623730951f;
    // A_COEF^16 (compile-time)
    constexpr float A16 =
        0.975f*0.975f*0.975f*0.975f*0.975f*0.975f*0.975f*0.975f*
        0.975f*0.975f*0.975f*0.975f*0.975f*0.975f*0.975f*0.975f;

    const int row = blockIdx.x;
    const float* __restrict__ xr  = x   + (size_t)row * T_LEN;
    float* __restrict__       orr = out + (size_t)row * T_LEN;

    const int tid  = threadIdx.x;
    const int base = tid * PER;

    // ---- 4 independent float4 loads (64B chunk per thread) ----
    float xv[PER];
    {
        float4 v0 = *(const float4*)(xr + base);
        float4 v1 = *(const float4*)(xr + base + 4);
        float4 v2 = *(const float4*)(xr + base + 8);
        float4 v3 = *(const float4*)(xr + base + 12);
        xv[0]=v0.x; xv[1]=v0.y; xv[2]=v0.z;  xv[3]=v0.w;
        xv[4]=v1.x; xv[5]=v1.y; xv[6]=v1.z;  xv[7]=v1.w;
        xv[8]=v2.x; xv[9]=v2.y; xv[10]=v2.z; xv[11]=v2.w;
        xv[12]=v3.x; xv[13]=v3.y; xv[14]=v3.z; xv[15]=v3.w;
    }

    // ---- local affine composition, KEEPING per-element offsets B_i ----
    // segment map after i+1 elems: y -> A_COEF^(i+1)*y + Bi[i]
    // t==0 (tid 0) is the absorbing map (A=0), making the row exact.
    float Bi[PER];
    float A;
    if (tid == 0) { Bi[0] = xv[0];          A = 0.0f; }
    else          { Bi[0] = S_COEF * xv[0]; A = A16;  }
#pragma unroll
    for (int i = 1; i < PER; ++i) {
        Bi[i] = fmaf(A_COEF, Bi[i-1], S_COEF * xv[i]);
    }
    float B = Bi[PER-1];

    // ---- inclusive scan of affine pairs within the 64-lane wave ----
    const int lane = tid & 63;
#pragma unroll
    for (int off = 1; off < 64; off <<= 1) {
        float Au = __shfl_up(A, off);
        float Bu = __shfl_up(B, off);
        if (lane >= off) {
            B = fmaf(A, Bu, B);   // (A,B) ∘ (Au,Bu)
            A = A * Au;
        }
    }

    // ---- cross-wave combine (4 waves) ----
    __shared__ float wA[NWAVE], wB[NWAVE];
    const int wid = tid >> 6;
    if (lane == 63) { wA[wid] = A; wB[wid] = B; }
    __syncthreads();

    // exclusive-within-wave = inclusive shifted down one lane
    float Aex = __shfl_up(A, 1);
    float Bex = __shfl_up(B, 1);
    if (lane == 0) { Aex = 1.0f; Bex = 0.0f; }

    // exclusive wave prefix: compose totals of waves 0..wid-1 in order
    float WB = 0.0f;
    for (int w = 0; w < wid; ++w) {
        WB = fmaf(wA[w], WB, wB[w]);
    }

    // smooth value entering this thread's segment
    // (tid 0: Aex=1, Bex=0, WB=0 -> y_in = 0, and its maps have A=0 anyway)
    float y_in = fmaf(Aex, WB, Bex);

    // ---- replay WITHOUT a dependent chain: smooth_i = ap_i*y_in + Bi[i] ----
    // ap starts at A_COEF and is multiplied by a literal each unrolled step,
    // so every power constant-folds.
    float ap = A_COEF;
#pragma unroll
    for (int i = 0; i < PER; ++i) {
        float sm = fmaf(ap, y_in, Bi[i]);
        ap *= A_COEF;
        // (smooth+eps)^(-alpha) via raw v_log_f32 / v_exp_f32 (safe range)
        float p = __builtin_amdgcn_exp2f(-ALPHA * __builtin_amdgcn_logf(sm + EPS));
        xv[i] = __builtin_amdgcn_sqrtf(fmaf(xv[i], p, DELTA)) - SQRT_DELTA;
    }

    // ---- 4 float4 stores (64B chunk per thread) ----
    {
        float4 v0, v1, v2, v3;
        v0.x=xv[0];  v0.y=xv[1];  v0.z=xv[2];  v0.w=xv[3];
        v1.x=xv[4];  v1.y=xv[5];  v1.z=xv[6];  v1.w=xv[7];
        v2.x=xv[8];  v2.y=xv[9];  v2.z=xv[10]; v2.w=xv[11];
        v3.x=xv[12]; v3.y=xv[13]; v3.z=xv[14]; v3.w=xv[15];
        *(float4*)(orr + base)      = v0;
        *(float4*)(orr + base + 4)  = v1;
        *(float4*)(orr + base + 8)  = v2;
        *(float4*)(orr + base + 12) = v3;
    }
}

extern "C" void kernel_launch(void* const* d_in, const int* in_sizes, int n_in,
                              void* d_out, int out_size, void* d_ws, size_t ws_size,
                              hipStream_t stream) {
    const float* x = (const float*)d_in[0];
    float* out = (float*)d_out;
    const int rows = in_sizes[0] / T_LEN;  // 64*128 = 8192
    pcen_kernel<<<rows, BLOCK, 0, stream>>>(x, out);
}

// Round 2
// 227.450 us; speedup vs baseline: 1.0276x; 1.0276x over previous
//
#include <hip/hip_runtime.h>
#include <math.h>

// PCEN: out = (x / (smooth + eps)^alpha + delta)^r - delta^r
// smooth[0]=x[0]; smooth[t] = (1-S)*smooth[t-1] + S*x[t]
// x: [64,128,4096] fp32 -> 8192 rows of T=4096.
//
// One block of 256 threads per row, PER=16 elements per thread.
// Round-1 lesson: thread-contiguous segments loaded directly from global
// have a 64B inter-lane stride -> 4x sector requests/instr, latency-bound
// (86us, 29% HBM, 16% VALU). Fix: keep the PER=16 scan amortization but
// restore UNIT-STRIDE global access and transpose through LDS:
//   global (coalesced float4, lane-contiguous) -> LDS -> per-thread
//   contiguous segment (ds_read_b128) -> compute -> LDS -> coalesced store.
// The segment access is the documented 32-way bank-conflict pattern, so all
// LDS addresses go through an address-only XOR swizzle
//   a ^= ((a>>7)&7)<<2        (flips dword bits[4:2], preserves 16B align)
// which is conflict-free for BOTH the coalesced (4t+1024c) and segment
// (16t+4j) patterns: 8 lanes per 4-bank group in each case.
// Affine-map scan with stored per-element offsets: replay is 16 independent
// fmas (smooth_i = A^(i+1)*y_in + Bi[i], powers constant-folded).

#define T_LEN 4096
#define BLOCK 256
#define PER   16   // 256*16 = 4096
#define NWAVE (BLOCK / 64)

__device__ __forceinline__ int swz(int a) {
    return a ^ (((a >> 7) & 7) << 2);
}

__global__ __launch_bounds__(BLOCK) void pcen_kernel(const float* __restrict__ x,
                                                     float* __restrict__ out) {
    constexpr float A_COEF = 0.975f;   // 1 - S
    constexpr float S_COEF = 0.025f;   // S
    constexpr float ALPHA  = 0.98f;
    constexpr float EPS    = 1e-6f;
    constexpr float DELTA  = 2.0f;
    constexpr float SQRT_DELTA = 1.4142135623730951f;
    constexpr float A16 =
        0.975f*0.975f*0.975f*0.975f*0.975f*0.975f*0.975f*0.975f*
        0.975f*0.975f*0.975f*0.975f*0.975f*0.975f*0.975f*0.975f;

    __shared__ float lds[T_LEN];           // 16 KB row tile
    __shared__ float wA[NWAVE], wB[NWAVE];

    const int row = blockIdx.x;
    const float* __restrict__ xr  = x   + (size_t)row * T_LEN;
    float* __restrict__       orr = out + (size_t)row * T_LEN;
    const int tid = threadIdx.x;

    // ---- phase 1: unit-stride coalesced load -> swizzled LDS ----
    // thread t covers dwords 4t + 1024c  (lane-contiguous per instr)
#pragma unroll
    for (int c = 0; c < 4; ++c) {
        const int a = tid * 4 + c * 1024;
        float4 v = *(const float4*)(xr + a);
        *(float4*)(&lds[swz(a)]) = v;
    }
    __syncthreads();

    // ---- phase 2: read my contiguous 16-element segment ----
    float xv[PER];
#pragma unroll
    for (int j = 0; j < 4; ++j) {
        const int a = tid * PER + j * 4;
        float4 v = *(const float4*)(&lds[swz(a)]);
        xv[j*4+0] = v.x; xv[j*4+1] = v.y; xv[j*4+2] = v.z; xv[j*4+3] = v.w;
    }

    // ---- local affine composition, keeping per-element offsets B_i ----
    // after i+1 elems: y -> A_COEF^(i+1)*y + Bi[i]; tid0 absorbing (A=0)
    float Bi[PER];
    float A;
    if (tid == 0) { Bi[0] = xv[0];          A = 0.0f; }
    else          { Bi[0] = S_COEF * xv[0]; A = A16;  }
#pragma unroll
    for (int i = 1; i < PER; ++i) {
        Bi[i] = fmaf(A_COEF, Bi[i-1], S_COEF * xv[i]);
    }
    float B = Bi[PER-1];

    // ---- inclusive scan of affine pairs within the 64-lane wave ----
    const int lane = tid & 63;
#pragma unroll
    for (int off = 1; off < 64; off <<= 1) {
        float Au = __shfl_up(A, off);
        float Bu = __shfl_up(B, off);
        if (lane >= off) {
            B = fmaf(A, Bu, B);   // (A,B) ∘ (Au,Bu)
            A = A * Au;
        }
    }

    // ---- cross-wave combine (4 waves) ----
    const int wid = tid >> 6;
    if (lane == 63) { wA[wid] = A; wB[wid] = B; }
    __syncthreads();   // also the WAR guard for reusing lds[] below

    float Aex = __shfl_up(A, 1);
    float Bex = __shfl_up(B, 1);
    if (lane == 0) { Aex = 1.0f; Bex = 0.0f; }

    float WB = 0.0f;
    for (int w = 0; w < wid; ++w) {
        WB = fmaf(wA[w], WB, wB[w]);
    }
    // smooth entering this thread's segment (tid0: y_in=0, maps have A=0)
    float y_in = fmaf(Aex, WB, Bex);

    // ---- replay: 16 independent fmas, powers constant-folded ----
    float ap = A_COEF;
#pragma unroll
    for (int i = 0; i < PER; ++i) {
        float sm = fmaf(ap, y_in, Bi[i]);
        ap *= A_COEF;
        // (smooth+eps)^(-alpha) via raw v_log/v_exp (y+eps in [1e-6,~1])
        float p = __builtin_amdgcn_exp2f(-ALPHA * __builtin_amdgcn_logf(sm + EPS));
        xv[i] = __builtin_amdgcn_sqrtf(fmaf(xv[i], p, DELTA)) - SQRT_DELTA;
    }

    // ---- phase 4: segment -> swizzled LDS ----
#pragma unroll
    for (int j = 0; j < 4; ++j) {
        const int a = tid * PER + j * 4;
        float4 v;
        v.x = xv[j*4+0]; v.y = xv[j*4+1]; v.z = xv[j*4+2]; v.w = xv[j*4+3];
        *(float4*)(&lds[swz(a)]) = v;
    }
    __syncthreads();

    // ---- phase 5: coalesced read from LDS -> unit-stride global store ----
#pragma unroll
    for (int c = 0; c < 4; ++c) {
        const int a = tid * 4 + c * 1024;
        float4 v = *(const float4*)(&lds[swz(a)]);
        *(float4*)(orr + a) = v;
    }
}

extern "C" void kernel_launch(void* const* d_in, const int* in_sizes, int n_in,
                              void* d_out, int out_size, void* d_ws, size_t ws_size,
                              hipStream_t stream) {
    const float* x = (const float*)d_in[0];
    float* out = (float*)d_out;
    const int rows = in_sizes[0] / T_LEN;  // 64*128 = 8192
    pcen_kernel<<<rows, BLOCK, 0, stream>>>(x, out);
}